// Round 9
// baseline (263.127 us; speedup 1.0000x reference)
//
#include <hip/hip_runtime.h>

#define NGS 25
#define NGX 40
#define NGY 40
#define KK  64
#define NB2 4
#define NYY 1000
#define PTOT 625
#define PC  32
#define DAMP 0.01f

typedef __attribute__((ext_vector_type(8))) short short8;
typedef __attribute__((ext_vector_type(4))) float f32x4;

__device__ __forceinline__ short bf16_rn(float x) {
  unsigned u = __float_as_uint(x);
  u = u + 0x7fffu + ((u >> 16) & 1u);
  return (short)(u >> 16);
}
__device__ __forceinline__ float bf16_tof(short s) {
  return __uint_as_float(((unsigned)(unsigned short)s) << 16);
}

// ---------------- Kernel 1: barrier-free per-wave MFMA Gram + GJ solve -------
// Each wave owns a private LDS plane pair (80x32 bf16 hi/lo) and processes
// chunks w, w+4, ..., w+16 with NO __syncthreads in the main loop: DS ops are
// in-order per wave, so ds_write->ds_read on the private plane is safe, and
// next-chunk global loads stay in flight across convert+MFMA (no barrier =>
// no compiler-forced vmcnt(0) drain). Each wave computes the FULL G from its
// p-slice; symmetry => only 10 upper tiles (30 MFMA/chunk vs 48 equivalent).
// 4-step barriered reduction into Gs at the end, then register Gauss-Jordan.
__global__ __launch_bounds__(256) void k_gram_solve(
    const float* __restrict__ xin, const float* __restrict__ hist,
    float* __restrict__ AG)
{
  // 4 waves x (hi,lo) x 80 x 32 shorts = 41 KB, + prow
  __shared__ __align__(16) short smem[4 * 2 * 80 * PC + 288];
  float (*Gs)[KK + 5] = (float (*)[KK + 5])smem;   // 64x69 fp32 aliases planes 0/1
  float* prow = (float*)(smem + 4 * 2 * 80 * PC);  // 2x72 fp32 ping-pong

  const int tile = blockIdx.x;
  const int gx = tile / NGY, gy = tile % NGY;
  const size_t base = (size_t)(gx * NGS) * NYY + (size_t)(gy * NGS);
  const int tid  = threadIdx.x;
  const int wave = tid >> 6;
  const int lane = tid & 63;
  const int u    = lane >> 4;     // k-group 0..3
  const int col  = lane & 15;

  short* Whi = smem + wave * (2 * 80 * PC);
  short* Wlo = Whi + 80 * PC;

  // zero-pad rows 68..79 of this wave's planes (X fragment rows col>=4)
  for (int i = lane; i < 12 * PC; i += 64) { Whi[68 * PC + i] = 0; Wlo[68 * PC + i] = 0; }

  f32x4 accG[10];   // upper-triangle 16x16 tiles (si<=sj)
  f32x4 accA[4];
  #pragma unroll
  for (int j = 0; j < 10; ++j) { accG[j].x = 0.f; accG[j].y = 0.f; accG[j].z = 0.f; accG[j].w = 0.f; }
  #pragma unroll
  for (int j = 0; j < 4; ++j) { accA[j].x = 0.f; accA[j].y = 0.f; accA[j].z = 0.f; accA[j].w = 0.f; }

  const int pp = lane & 31;   // p within chunk
  const int rh = lane >> 5;   // row parity (0/1)

  #define STW(r, val) { \
    const short h = (short)(__float_as_uint(val) >> 16); \
    const short l = bf16_rn((val) - bf16_tof(h)); \
    const int off = (r) * PC + ((((pp >> 3) ^ ((r) & 3)) << 3) | (pp & 7)); \
    Whi[off] = h; Wlo[off] = l; }

  for (int cw = 0; cw < 5; ++cw) {
    const int ch = wave + 4 * cw;
    const int p = ch * PC + pp;
    const bool inb = (p < PTOT);
    const int px = p / NGS, py = p - px * NGS;
    const size_t a = base + (size_t)px * NYY + py;

    // ---- 2 batches of 17 loads (rows 2*it+rh): issue, then convert+write
    float v0[17], v1[17];
    #pragma unroll
    for (int it = 0; it < 17; ++it)
      v0[it] = inb ? hist[(size_t)(2 * it + rh) * 1000000 + a] : 0.f;
    #pragma unroll
    for (int it = 0; it < 17; ++it) {
      const int r = 34 + 2 * it + rh;
      v1[it] = inb ? ((r < KK) ? hist[(size_t)r * 1000000 + a]
                               : xin[(size_t)(r - KK) * 1000000 + a]) : 0.f;
    }
    #pragma unroll
    for (int it = 0; it < 17; ++it) STW(2 * it + rh, v0[it]);
    #pragma unroll
    for (int it = 0; it < 17; ++it) STW(34 + 2 * it + rh, v1[it]);

    // ---- fragments (one 32-K MFMA step; k8 group = u)
    #define FRG(P, r) (*(const short8*)&P[(r) * PC + (((u) ^ ((r) & 3)) << 3)])
    short8 fh[4], fl[4];
    #pragma unroll
    for (int s = 0; s < 4; ++s) { fh[s] = FRG(Whi, 16 * s + col); fl[s] = FRG(Wlo, 16 * s + col); }
    const short8 xh = FRG(Whi, KK + col);
    const short8 xl = FRG(Wlo, KK + col);
    #undef FRG

    // ---- G upper tiles: (si,sj) si<=sj, 3 hi/lo split terms each
    #pragma unroll
    for (int si = 0; si < 4; ++si)
      #pragma unroll
      for (int sj = 0; sj < 4; ++sj) {
        if (sj >= si) {
          const int ix = si * 4 - (si * (si + 1)) / 2 + sj;
          accG[ix] = __builtin_amdgcn_mfma_f32_16x16x32_bf16(fh[si], fh[sj], accG[ix], 0, 0, 0);
          accG[ix] = __builtin_amdgcn_mfma_f32_16x16x32_bf16(fh[si], fl[sj], accG[ix], 0, 0, 0);
          accG[ix] = __builtin_amdgcn_mfma_f32_16x16x32_bf16(fl[si], fh[sj], accG[ix], 0, 0, 0);
        }
      }
    // ---- A tiles: X (A-operand, channel=col) x V-block s
    #pragma unroll
    for (int s = 0; s < 4; ++s) {
      accA[s] = __builtin_amdgcn_mfma_f32_16x16x32_bf16(xh, fh[s], accA[s], 0, 0, 0);
      accA[s] = __builtin_amdgcn_mfma_f32_16x16x32_bf16(xh, fl[s], accA[s], 0, 0, 0);
      accA[s] = __builtin_amdgcn_mfma_f32_16x16x32_bf16(xl, fh[s], accA[s], 0, 0, 0);
    }
  }
  #undef STW

  // ---- cross-wave reduction into Gs (+damping, symmetric mirror) -----------
  __syncthreads();   // all waves done reading their planes (Gs aliases them)
  for (int g = 0; g < 4; ++g) {
    if (wave == g) {
      #pragma unroll
      for (int si = 0; si < 4; ++si)
        #pragma unroll
        for (int sj = 0; sj < 4; ++sj) {
          if (sj >= si) {
            const int ix = si * 4 - (si * (si + 1)) / 2 + sj;
            #pragma unroll
            for (int q = 0; q < 4; ++q) {
              const float val = (q == 0) ? accG[ix].x : (q == 1) ? accG[ix].y
                              : (q == 2) ? accG[ix].z : accG[ix].w;
              const int r0 = 16 * si + 4 * u + q;
              const int c0 = 16 * sj + col;
              if (g == 0) {
                Gs[r0][c0] = val + ((r0 == c0) ? DAMP : 0.f);
                if (si != sj) Gs[c0][r0] = val;
              } else {
                Gs[r0][c0] += val;
                if (si != sj) Gs[c0][r0] += val;
              }
            }
          }
        }
      if (lane < 16) {
        #pragma unroll
        for (int s = 0; s < 4; ++s) {
          #pragma unroll
          for (int q = 0; q < 4; ++q) {
            const float val = (q == 0) ? accA[s].x : (q == 1) ? accA[s].y
                            : (q == 2) ? accA[s].z : accA[s].w;
            if (g == 0) Gs[16 * s + lane][KK + q] = val;
            else        Gs[16 * s + lane][KK + q] += val;
          }
        }
      }
    }
    __syncthreads();
  }

  // ---- register Gauss-Jordan: thread (ei,eq) owns cols {eq+4jj} of row ei ----
  const int ei = tid >> 2, eq = tid & 3;
  float w[17];
  #pragma unroll
  for (int jj = 0; jj < 17; ++jj) w[jj] = Gs[ei][4 * jj + eq];

  float myDiag = 1.f;
  if (ei == 0) {
    #pragma unroll
    for (int jj = 0; jj < 17; ++jj) prow[4 * jj + eq] = w[jj];
  }
  __syncthreads();

  #pragma unroll
  for (int k = 0; k < KK; ++k) {
    const float* pr = prow + (k & 1) * 72;
    const float piv = pr[k];
    const float num = __shfl(w[k >> 2], (lane & ~3) | (k & 3), 64);
    const float f = (ei == k) ? 0.f : (num / piv);
    if (ei == k) myDiag = piv;
    #pragma unroll
    for (int jj = (k < 3 ? 0 : (k - 2) >> 2); jj < 17; ++jj)
      w[jj] -= f * pr[4 * jj + eq];
    if (k < KK - 1) {
      if (ei == k + 1) {
        float* pw = prow + ((k + 1) & 1) * 72;
        #pragma unroll
        for (int jj = 0; jj < 17; ++jj) pw[4 * jj + eq] = w[jj];
      }
    }
    __syncthreads();
  }

  AG[(size_t)tile * 256 + eq * 64 + ei] = w[16] / myDiag;
}

// ---------------- Kernel 2: Y = AG * V, scatter to output ---------------------
__global__ __launch_bounds__(256) void k_project(
    const float* __restrict__ hist, const float* __restrict__ AG,
    float* __restrict__ out)
{
  __shared__ float ag[KK][NB2];   // ag[k][c]
  const int tile = blockIdx.x;
  const int gx = tile / NGY, gy = tile % NGY;
  const size_t base = (size_t)(gx * NGS) * NYY + (size_t)(gy * NGS);
  const int tid = threadIdx.x;
  {
    const int c = tid >> 6, k = tid & 63;
    ag[k][c] = AG[(size_t)tile * 256 + tid];   // AG[c][k] -> ag[k][c]
  }
  __syncthreads();

  const int p1 = tid, p2 = tid + 256, p3 = tid + 512;
  const int a1 = (p1 / NGS) * NYY + (p1 % NGS);
  const int a2 = (p2 / NGS) * NYY + (p2 % NGS);
  const bool has3 = (p3 < PTOT);
  const int a3 = has3 ? ((p3 / NGS) * NYY + (p3 % NGS)) : 0;

  float o1[4] = {0,0,0,0}, o2[4] = {0,0,0,0}, o3[4] = {0,0,0,0};
  const float4* ag4 = (const float4*)ag;

  #pragma unroll 4
  for (int k = 0; k < KK; ++k) {
    const size_t ko = (size_t)k * 1000000 + base;
    const float v1 = hist[ko + a1];
    const float v2 = hist[ko + a2];
    const float v3 = has3 ? hist[ko + a3] : 0.f;
    const float4 w = ag4[k];
    o1[0] += w.x * v1; o1[1] += w.y * v1; o1[2] += w.z * v1; o1[3] += w.w * v1;
    o2[0] += w.x * v2; o2[1] += w.y * v2; o2[2] += w.z * v2; o2[3] += w.w * v2;
    o3[0] += w.x * v3; o3[1] += w.y * v3; o3[2] += w.z * v3; o3[3] += w.w * v3;
  }

  out[(size_t)0 * 1000000 + base + a1] = o1[0];
  out[(size_t)1 * 1000000 + base + a1] = o1[1];
  out[(size_t)2 * 1000000 + base + a1] = o1[2];
  out[(size_t)3 * 1000000 + base + a1] = o1[3];
  out[(size_t)0 * 1000000 + base + a2] = o2[0];
  out[(size_t)1 * 1000000 + base + a2] = o2[1];
  out[(size_t)2 * 1000000 + base + a2] = o2[2];
  out[(size_t)3 * 1000000 + base + a2] = o2[3];
  if (has3) {
    out[(size_t)0 * 1000000 + base + a3] = o3[0];
    out[(size_t)1 * 1000000 + base + a3] = o3[1];
    out[(size_t)2 * 1000000 + base + a3] = o3[2];
    out[(size_t)3 * 1000000 + base + a3] = o3[3];
  }
}

extern "C" void kernel_launch(void* const* d_in, const int* in_sizes, int n_in,
                              void* d_out, int out_size, void* d_ws, size_t ws_size,
                              hipStream_t stream) {
  const float* xin  = (const float*)d_in[0];   // local_x  (1,4,1000,1000)
  const float* hist = (const float*)d_in[1];   // ms_history (1,16,4,1000,1000)
  float* out = (float*)d_out;
  float* AG  = (float*)d_ws;                   // 1600 * 256 floats = 1.6 MB

  k_gram_solve<<<NGX * NGY, 256, 0, stream>>>(xin, hist, AG);
  k_project  <<<NGX * NGY, 256, 0, stream>>>(hist, AG, out);
}

// Round 10
// 249.088 us; speedup vs baseline: 1.0564x; 1.0564x over previous
//
#include <hip/hip_runtime.h>

#define NGS 25
#define NGX 40
#define NGY 40
#define KK  64
#define NB2 4
#define NYY 1000
#define DAMP 0.01f

typedef __attribute__((ext_vector_type(8))) short short8;
typedef __attribute__((ext_vector_type(4))) float f32x4;

__device__ __forceinline__ short bf16_rn(float x) {
  unsigned u = __float_as_uint(x);
  u = u + 0x7fffu + ((u >> 16) & 1u);
  return (short)(u >> 16);
}
__device__ __forceinline__ float bf16_tof(short s) {
  return __uint_as_float(((unsigned)(unsigned short)s) << 16);
}

// ---------------- Kernel 1: LDS-free direct-fragment MFMA Gram + GJ solve ----
// K-step = one spatial row of the tile (25 valid p, zero-padded to 32 k-slots).
// Lane l's fragment V[16s+(l&15)][8u+e] is 8 CONSECUTIVE floats in memory ->
// load straight to registers, cvt to bf16 hi/lo, MFMA. No LDS staging, no
// barriers in the main loop (k_project-style streaming, which measures 3.9TB/s
// on this exact DRAM pattern vs 2.2 for every LDS-staged variant).
// u=3 k-group loads py17..24 (in-bounds) and keeps only py24 in slot 0.
// Waves split rows r = wave, wave+4, ...; 4-phase LDS reduce + register GJ.
__global__ __launch_bounds__(256) void k_gram_solve(
    const float* __restrict__ xin, const float* __restrict__ hist,
    float* __restrict__ AG)
{
  __shared__ float Gs[KK][KK + 5];
  __shared__ float prow[144];

  const int tile = blockIdx.x;
  const int gx = tile / NGY, gy = tile % NGY;
  const size_t base = (size_t)(gx * NGS) * NYY + (size_t)(gy * NGS);
  const int tid  = threadIdx.x;
  const int wave = tid >> 6;
  const int lane = tid & 63;
  const int u    = lane >> 4;     // k-group 0..3
  const int col  = lane & 15;
  const bool tail = (u == 3);
  const int off  = tail ? 17 : (8 * u);   // py window start (tail shifts back)

  f32x4 accG[10];   // upper-triangle 16x16 tiles (si<=sj)
  f32x4 accA[4];
  #pragma unroll
  for (int j = 0; j < 10; ++j) { accG[j].x = 0.f; accG[j].y = 0.f; accG[j].z = 0.f; accG[j].w = 0.f; }
  #pragma unroll
  for (int j = 0; j < 4; ++j) { accA[j].x = 0.f; accA[j].y = 0.f; accA[j].z = 0.f; accA[j].w = 0.f; }

  const int xch = (col < 4) ? col : 3;    // clamped X channel (masked below)

  for (int r = wave; r < NGS; r += 4) {
    const size_t base_r = base + (size_t)r * NYY + off;

    short8 fh[5], fl[5];
    #pragma unroll
    for (int s = 0; s < 5; ++s) {
      const float* rp = (s < 4)
        ? (hist + (size_t)(16 * s + col) * 1000000 + base_r)
        : (xin  + (size_t)xch * 1000000 + base_r);
      float f[8];
      #pragma unroll
      for (int e = 0; e < 8; ++e) f[e] = rp[e];
      // tail group: keep only py24 (loaded slot 7) in k-slot 0, rest zero
      float g0 = tail ? f[7] : f[0];
      f[0] = g0;
      #pragma unroll
      for (int e = 1; e < 8; ++e) f[e] = tail ? 0.f : f[e];
      if (s == 4) {   // X block: rows (channels) 4..15 are zero
        const bool xv = (col < 4);
        #pragma unroll
        for (int e = 0; e < 8; ++e) f[e] = xv ? f[e] : 0.f;
      }
      short8 h8, l8;
      #pragma unroll
      for (int e = 0; e < 8; ++e) {
        const short h = (short)(__float_as_uint(f[e]) >> 16);
        h8[e] = h;
        l8[e] = bf16_rn(f[e] - bf16_tof(h));
      }
      fh[s] = h8; fl[s] = l8;
    }

    // ---- G upper tiles: (si,sj) si<=sj, 3 hi/lo split terms each
    #pragma unroll
    for (int si = 0; si < 4; ++si)
      #pragma unroll
      for (int sj = 0; sj < 4; ++sj) {
        if (sj >= si) {
          const int ix = si * 4 - (si * (si + 1)) / 2 + sj;
          accG[ix] = __builtin_amdgcn_mfma_f32_16x16x32_bf16(fh[si], fh[sj], accG[ix], 0, 0, 0);
          accG[ix] = __builtin_amdgcn_mfma_f32_16x16x32_bf16(fh[si], fl[sj], accG[ix], 0, 0, 0);
          accG[ix] = __builtin_amdgcn_mfma_f32_16x16x32_bf16(fl[si], fh[sj], accG[ix], 0, 0, 0);
        }
      }
    // ---- A tiles: X (A-operand, row=channel) x V-block s
    #pragma unroll
    for (int s = 0; s < 4; ++s) {
      accA[s] = __builtin_amdgcn_mfma_f32_16x16x32_bf16(fh[4], fh[s], accA[s], 0, 0, 0);
      accA[s] = __builtin_amdgcn_mfma_f32_16x16x32_bf16(fh[4], fl[s], accA[s], 0, 0, 0);
      accA[s] = __builtin_amdgcn_mfma_f32_16x16x32_bf16(fl[4], fh[s], accA[s], 0, 0, 0);
    }
  }

  // ---- cross-wave reduction into Gs (+damping, symmetric mirror) -----------
  __syncthreads();
  for (int g = 0; g < 4; ++g) {
    if (wave == g) {
      #pragma unroll
      for (int si = 0; si < 4; ++si)
        #pragma unroll
        for (int sj = 0; sj < 4; ++sj) {
          if (sj >= si) {
            const int ix = si * 4 - (si * (si + 1)) / 2 + sj;
            #pragma unroll
            for (int q = 0; q < 4; ++q) {
              const float val = (q == 0) ? accG[ix].x : (q == 1) ? accG[ix].y
                              : (q == 2) ? accG[ix].z : accG[ix].w;
              const int r0 = 16 * si + 4 * u + q;
              const int c0 = 16 * sj + col;
              if (g == 0) {
                Gs[r0][c0] = val + ((r0 == c0) ? DAMP : 0.f);
                if (si != sj) Gs[c0][r0] = val;
              } else {
                Gs[r0][c0] += val;
                if (si != sj) Gs[c0][r0] += val;
              }
            }
          }
        }
      if (lane < 16) {
        #pragma unroll
        for (int s = 0; s < 4; ++s) {
          #pragma unroll
          for (int q = 0; q < 4; ++q) {
            const float val = (q == 0) ? accA[s].x : (q == 1) ? accA[s].y
                            : (q == 2) ? accA[s].z : accA[s].w;
            if (g == 0) Gs[16 * s + lane][KK + q] = val;
            else        Gs[16 * s + lane][KK + q] += val;
          }
        }
      }
    }
    __syncthreads();
  }

  // ---- register Gauss-Jordan: thread (ei,eq) owns cols {eq+4jj} of row ei ----
  const int ei = tid >> 2, eq = tid & 3;
  float w[17];
  #pragma unroll
  for (int jj = 0; jj < 17; ++jj) w[jj] = Gs[ei][4 * jj + eq];

  float myDiag = 1.f;
  if (ei == 0) {
    #pragma unroll
    for (int jj = 0; jj < 17; ++jj) prow[4 * jj + eq] = w[jj];
  }
  __syncthreads();

  #pragma unroll
  for (int k = 0; k < KK; ++k) {
    const float* pr = prow + (k & 1) * 72;
    const float piv = pr[k];
    const float num = __shfl(w[k >> 2], (lane & ~3) | (k & 3), 64);
    const float f = (ei == k) ? 0.f : (num / piv);
    if (ei == k) myDiag = piv;
    #pragma unroll
    for (int jj = (k < 3 ? 0 : (k - 2) >> 2); jj < 17; ++jj)
      w[jj] -= f * pr[4 * jj + eq];
    if (k < KK - 1) {
      if (ei == k + 1) {
        float* pw = prow + ((k + 1) & 1) * 72;
        #pragma unroll
        for (int jj = 0; jj < 17; ++jj) pw[4 * jj + eq] = w[jj];
      }
    }
    __syncthreads();
  }

  AG[(size_t)tile * 256 + eq * 64 + ei] = w[16] / myDiag;
}

// ---------------- Kernel 2: Y = AG * V, scatter to output ---------------------
__global__ __launch_bounds__(256) void k_project(
    const float* __restrict__ hist, const float* __restrict__ AG,
    float* __restrict__ out)
{
  __shared__ float ag[KK][NB2];   // ag[k][c]
  const int tile = blockIdx.x;
  const int gx = tile / NGY, gy = tile % NGY;
  const size_t base = (size_t)(gx * NGS) * NYY + (size_t)(gy * NGS);
  const int tid = threadIdx.x;
  {
    const int c = tid >> 6, k = tid & 63;
    ag[k][c] = AG[(size_t)tile * 256 + tid];   // AG[c][k] -> ag[k][c]
  }
  __syncthreads();

  const int p1 = tid, p2 = tid + 256, p3 = tid + 512;
  const int a1 = (p1 / NGS) * NYY + (p1 % NGS);
  const int a2 = (p2 / NGS) * NYY + (p2 % NGS);
  const bool has3 = (p3 < 625);
  const int a3 = has3 ? ((p3 / NGS) * NYY + (p3 % NGS)) : 0;

  float o1[4] = {0,0,0,0}, o2[4] = {0,0,0,0}, o3[4] = {0,0,0,0};
  const float4* ag4 = (const float4*)ag;

  #pragma unroll 4
  for (int k = 0; k < KK; ++k) {
    const size_t ko = (size_t)k * 1000000 + base;
    const float v1 = hist[ko + a1];
    const float v2 = hist[ko + a2];
    const float v3 = has3 ? hist[ko + a3] : 0.f;
    const float4 w = ag4[k];
    o1[0] += w.x * v1; o1[1] += w.y * v1; o1[2] += w.z * v1; o1[3] += w.w * v1;
    o2[0] += w.x * v2; o2[1] += w.y * v2; o2[2] += w.z * v2; o2[3] += w.w * v2;
    o3[0] += w.x * v3; o3[1] += w.y * v3; o3[2] += w.z * v3; o3[3] += w.w * v3;
  }

  out[(size_t)0 * 1000000 + base + a1] = o1[0];
  out[(size_t)1 * 1000000 + base + a1] = o1[1];
  out[(size_t)2 * 1000000 + base + a1] = o1[2];
  out[(size_t)3 * 1000000 + base + a1] = o1[3];
  out[(size_t)0 * 1000000 + base + a2] = o2[0];
  out[(size_t)1 * 1000000 + base + a2] = o2[1];
  out[(size_t)2 * 1000000 + base + a2] = o2[2];
  out[(size_t)3 * 1000000 + base + a2] = o2[3];
  if (has3) {
    out[(size_t)0 * 1000000 + base + a3] = o3[0];
    out[(size_t)1 * 1000000 + base + a3] = o3[1];
    out[(size_t)2 * 1000000 + base + a3] = o3[2];
    out[(size_t)3 * 1000000 + base + a3] = o3[3];
  }
}

extern "C" void kernel_launch(void* const* d_in, const int* in_sizes, int n_in,
                              void* d_out, int out_size, void* d_ws, size_t ws_size,
                              hipStream_t stream) {
  const float* xin  = (const float*)d_in[0];   // local_x  (1,4,1000,1000)
  const float* hist = (const float*)d_in[1];   // ms_history (1,16,4,1000,1000)
  float* out = (float*)d_out;
  float* AG  = (float*)d_ws;                   // 1600 * 256 floats = 1.6 MB

  k_gram_solve<<<NGX * NGY, 256, 0, stream>>>(xin, hist, AG);
  k_project  <<<NGX * NGY, 256, 0, stream>>>(hist, AG, out);
}

// Round 11
// 243.865 us; speedup vs baseline: 1.0790x; 1.0214x over previous
//
#include <hip/hip_runtime.h>

#define NGS 25
#define NGX 40
#define NGY 40
#define KK  64
#define NB2 4
#define NYY 1000
#define DAMP 0.01f

typedef __attribute__((ext_vector_type(8))) short short8;
typedef __attribute__((ext_vector_type(4))) float f32x4;

__device__ __forceinline__ short bf16_rn(float x) {
  unsigned u = __float_as_uint(x);
  u = u + 0x7fffu + ((u >> 16) & 1u);
  return (short)(u >> 16);
}
__device__ __forceinline__ float bf16_tof(short s) {
  return __uint_as_float(((unsigned)(unsigned short)s) << 16);
}

// ---------------- Kernel 1: pure-streaming direct-fragment MFMA Gram ---------
// Round-10 structure WITHOUT the in-kernel solve: blocks stream 100% of their
// lifetime (the 64-barrier Gauss-Jordan was time-sharing residency slots and
// diluting in-flight memory requests to ~2KB/CU -> 1.7TB/s). Writes G(+damp)
// and A as a 64x68 fp32 panel per tile into ws; k_solve does the GJ.
__global__ __launch_bounds__(256) void k_gram(
    const float* __restrict__ xin, const float* __restrict__ hist,
    float* __restrict__ Gws)
{
  __shared__ float Gs[KK][KK + 5];

  const int tile = blockIdx.x;
  const int gx = tile / NGY, gy = tile % NGY;
  const size_t base = (size_t)(gx * NGS) * NYY + (size_t)(gy * NGS);
  const int tid  = threadIdx.x;
  const int wave = tid >> 6;
  const int lane = tid & 63;
  const int u    = lane >> 4;     // k-group 0..3
  const int col  = lane & 15;
  const bool tail = (u == 3);
  const int off  = tail ? 17 : (8 * u);   // py window start (tail shifts back)

  f32x4 accG[10];   // upper-triangle 16x16 tiles (si<=sj)
  f32x4 accA[4];
  #pragma unroll
  for (int j = 0; j < 10; ++j) { accG[j].x = 0.f; accG[j].y = 0.f; accG[j].z = 0.f; accG[j].w = 0.f; }
  #pragma unroll
  for (int j = 0; j < 4; ++j) { accA[j].x = 0.f; accA[j].y = 0.f; accA[j].z = 0.f; accA[j].w = 0.f; }

  const int xch = (col < 4) ? col : 3;    // clamped X channel (masked below)

  for (int r = wave; r < NGS; r += 4) {
    const size_t base_r = base + (size_t)r * NYY + off;

    short8 fh[5], fl[5];
    #pragma unroll
    for (int s = 0; s < 5; ++s) {
      const float* rp = (s < 4)
        ? (hist + (size_t)(16 * s + col) * 1000000 + base_r)
        : (xin  + (size_t)xch * 1000000 + base_r);
      float f[8];
      #pragma unroll
      for (int e = 0; e < 8; ++e) f[e] = rp[e];
      // tail group: keep only py24 (loaded slot 7) in k-slot 0, rest zero
      float g0 = tail ? f[7] : f[0];
      f[0] = g0;
      #pragma unroll
      for (int e = 1; e < 8; ++e) f[e] = tail ? 0.f : f[e];
      if (s == 4) {   // X block: rows (channels) 4..15 are zero
        const bool xv = (col < 4);
        #pragma unroll
        for (int e = 0; e < 8; ++e) f[e] = xv ? f[e] : 0.f;
      }
      short8 h8, l8;
      #pragma unroll
      for (int e = 0; e < 8; ++e) {
        const short h = (short)(__float_as_uint(f[e]) >> 16);
        h8[e] = h;
        l8[e] = bf16_rn(f[e] - bf16_tof(h));
      }
      fh[s] = h8; fl[s] = l8;
    }

    // ---- G upper tiles: (si,sj) si<=sj, 3 hi/lo split terms each
    #pragma unroll
    for (int si = 0; si < 4; ++si)
      #pragma unroll
      for (int sj = 0; sj < 4; ++sj) {
        if (sj >= si) {
          const int ix = si * 4 - (si * (si + 1)) / 2 + sj;
          accG[ix] = __builtin_amdgcn_mfma_f32_16x16x32_bf16(fh[si], fh[sj], accG[ix], 0, 0, 0);
          accG[ix] = __builtin_amdgcn_mfma_f32_16x16x32_bf16(fh[si], fl[sj], accG[ix], 0, 0, 0);
          accG[ix] = __builtin_amdgcn_mfma_f32_16x16x32_bf16(fl[si], fh[sj], accG[ix], 0, 0, 0);
        }
      }
    // ---- A tiles: X (A-operand, row=channel) x V-block s
    #pragma unroll
    for (int s = 0; s < 4; ++s) {
      accA[s] = __builtin_amdgcn_mfma_f32_16x16x32_bf16(fh[4], fh[s], accA[s], 0, 0, 0);
      accA[s] = __builtin_amdgcn_mfma_f32_16x16x32_bf16(fh[4], fl[s], accA[s], 0, 0, 0);
      accA[s] = __builtin_amdgcn_mfma_f32_16x16x32_bf16(fl[4], fh[s], accA[s], 0, 0, 0);
    }
  }

  // ---- cross-wave reduction into Gs (+damping, symmetric mirror) -----------
  __syncthreads();
  for (int g = 0; g < 4; ++g) {
    if (wave == g) {
      #pragma unroll
      for (int si = 0; si < 4; ++si)
        #pragma unroll
        for (int sj = 0; sj < 4; ++sj) {
          if (sj >= si) {
            const int ix = si * 4 - (si * (si + 1)) / 2 + sj;
            #pragma unroll
            for (int q = 0; q < 4; ++q) {
              const float val = (q == 0) ? accG[ix].x : (q == 1) ? accG[ix].y
                              : (q == 2) ? accG[ix].z : accG[ix].w;
              const int r0 = 16 * si + 4 * u + q;
              const int c0 = 16 * sj + col;
              if (g == 0) {
                Gs[r0][c0] = val + ((r0 == c0) ? DAMP : 0.f);
                if (si != sj) Gs[c0][r0] = val;
              } else {
                Gs[r0][c0] += val;
                if (si != sj) Gs[c0][r0] += val;
              }
            }
          }
        }
      if (lane < 16) {
        #pragma unroll
        for (int s = 0; s < 4; ++s) {
          #pragma unroll
          for (int q = 0; q < 4; ++q) {
            const float val = (q == 0) ? accA[s].x : (q == 1) ? accA[s].y
                            : (q == 2) ? accA[s].z : accA[s].w;
            if (g == 0) Gs[16 * s + lane][KK + q] = val;
            else        Gs[16 * s + lane][KK + q] += val;
          }
        }
      }
    }
    __syncthreads();
  }

  // ---- write 64x68 panel (G | A^T) to workspace, coalesced ------------------
  float* dst = Gws + (size_t)tile * (KK * 68);
  for (int idx = tid; idx < KK * 68; idx += 256) {
    const int r = idx / 68, c = idx - r * 68;
    dst[idx] = Gs[r][c];
  }
}

// ---------------- Kernel 1b: per-tile register Gauss-Jordan solve -> AG ------
// Tiny footprint (576B LDS, low VGPR) -> high residency; GJ barrier latency
// hidden by many concurrent blocks. Reads the L2/L3-warm G panels.
__global__ __launch_bounds__(256) void k_solve(
    const float* __restrict__ Gws, float* __restrict__ AG)
{
  __shared__ float prow[144];
  const int tile = blockIdx.x;
  const int tid  = threadIdx.x;
  const int lane = tid & 63;
  const int ei = tid >> 2, eq = tid & 3;
  const float* Gt = Gws + (size_t)tile * (KK * 68);

  float w[17];
  #pragma unroll
  for (int jj = 0; jj < 17; ++jj) w[jj] = Gt[ei * 68 + 4 * jj + eq];

  float myDiag = 1.f;
  if (ei == 0) {
    #pragma unroll
    for (int jj = 0; jj < 17; ++jj) prow[4 * jj + eq] = w[jj];
  }
  __syncthreads();

  #pragma unroll
  for (int k = 0; k < KK; ++k) {
    const float* pr = prow + (k & 1) * 72;
    const float piv = pr[k];
    const float num = __shfl(w[k >> 2], (lane & ~3) | (k & 3), 64);
    const float f = (ei == k) ? 0.f : (num / piv);
    if (ei == k) myDiag = piv;
    #pragma unroll
    for (int jj = (k < 3 ? 0 : (k - 2) >> 2); jj < 17; ++jj)
      w[jj] -= f * pr[4 * jj + eq];
    if (k < KK - 1) {
      if (ei == k + 1) {
        float* pw = prow + ((k + 1) & 1) * 72;
        #pragma unroll
        for (int jj = 0; jj < 17; ++jj) pw[4 * jj + eq] = w[jj];
      }
    }
    __syncthreads();
  }

  AG[(size_t)tile * 256 + eq * 64 + ei] = w[16] / myDiag;
}

// ---------------- Kernel 2: Y = AG * V, scatter to output ---------------------
__global__ __launch_bounds__(256) void k_project(
    const float* __restrict__ hist, const float* __restrict__ AG,
    float* __restrict__ out)
{
  __shared__ float ag[KK][NB2];   // ag[k][c]
  const int tile = blockIdx.x;
  const int gx = tile / NGY, gy = tile % NGY;
  const size_t base = (size_t)(gx * NGS) * NYY + (size_t)(gy * NGS);
  const int tid = threadIdx.x;
  {
    const int c = tid >> 6, k = tid & 63;
    ag[k][c] = AG[(size_t)tile * 256 + tid];   // AG[c][k] -> ag[k][c]
  }
  __syncthreads();

  const int p1 = tid, p2 = tid + 256, p3 = tid + 512;
  const int a1 = (p1 / NGS) * NYY + (p1 % NGS);
  const int a2 = (p2 / NGS) * NYY + (p2 % NGS);
  const bool has3 = (p3 < 625);
  const int a3 = has3 ? ((p3 / NGS) * NYY + (p3 % NGS)) : 0;

  float o1[4] = {0,0,0,0}, o2[4] = {0,0,0,0}, o3[4] = {0,0,0,0};
  const float4* ag4 = (const float4*)ag;

  #pragma unroll 4
  for (int k = 0; k < KK; ++k) {
    const size_t ko = (size_t)k * 1000000 + base;
    const float v1 = hist[ko + a1];
    const float v2 = hist[ko + a2];
    const float v3 = has3 ? hist[ko + a3] : 0.f;
    const float4 w = ag4[k];
    o1[0] += w.x * v1; o1[1] += w.y * v1; o1[2] += w.z * v1; o1[3] += w.w * v1;
    o2[0] += w.x * v2; o2[1] += w.y * v2; o2[2] += w.z * v2; o2[3] += w.w * v2;
    o3[0] += w.x * v3; o3[1] += w.y * v3; o3[2] += w.z * v3; o3[3] += w.w * v3;
  }

  out[(size_t)0 * 1000000 + base + a1] = o1[0];
  out[(size_t)1 * 1000000 + base + a1] = o1[1];
  out[(size_t)2 * 1000000 + base + a1] = o1[2];
  out[(size_t)3 * 1000000 + base + a1] = o1[3];
  out[(size_t)0 * 1000000 + base + a2] = o2[0];
  out[(size_t)1 * 1000000 + base + a2] = o2[1];
  out[(size_t)2 * 1000000 + base + a2] = o2[2];
  out[(size_t)3 * 1000000 + base + a2] = o2[3];
  if (has3) {
    out[(size_t)0 * 1000000 + base + a3] = o3[0];
    out[(size_t)1 * 1000000 + base + a3] = o3[1];
    out[(size_t)2 * 1000000 + base + a3] = o3[2];
    out[(size_t)3 * 1000000 + base + a3] = o3[3];
  }
}

extern "C" void kernel_launch(void* const* d_in, const int* in_sizes, int n_in,
                              void* d_out, int out_size, void* d_ws, size_t ws_size,
                              hipStream_t stream) {
  const float* xin  = (const float*)d_in[0];   // local_x  (1,4,1000,1000)
  const float* hist = (const float*)d_in[1];   // ms_history (1,16,4,1000,1000)
  float* out = (float*)d_out;
  float* AG  = (float*)d_ws;                       // 1600*256 floats = 1.6 MB
  float* Gws = (float*)d_ws + 1600 * 256;          // 1600 * 64*68 floats = 27.9 MB

  k_gram   <<<NGX * NGY, 256, 0, stream>>>(xin, hist, Gws);
  k_solve  <<<NGX * NGY, 256, 0, stream>>>(Gws, AG);
  k_project<<<NGX * NGY, 256, 0, stream>>>(hist, AG, out);
}

// Round 12
// 196.071 us; speedup vs baseline: 1.3420x; 1.2438x over previous
//
#include <hip/hip_runtime.h>

#define NGS 25
#define NGX 40
#define NGY 40
#define KK  64
#define NB2 4
#define NYY 1000
#define DAMP 0.01f

typedef __attribute__((ext_vector_type(8))) short short8;
typedef __attribute__((ext_vector_type(4))) float f32x4;

__device__ __forceinline__ short bf16_rn(float x) {
  unsigned u = __float_as_uint(x);
  u = u + 0x7fffu + ((u >> 16) & 1u);
  return (short)(u >> 16);
}
__device__ __forceinline__ float bf16_tof(short s) {
  return __uint_as_float(((unsigned)(unsigned short)s) << 16);
}

// ---------------- Kernel 1: pipelined direct-fragment MFMA Gram --------------
// 2-deep register double-buffer across the r-loop: iteration I+1's 40 loads
// issue BEFORE iteration I's cvt+MFMA consume, so HBM latency hides under
// ~700cy of compute each iteration (previous rolled loop serialized
// load->wait->cvt->MFMA per iteration => 2.1 TB/s wall). Uniform 7 stages
// (r>=25 -> zeroed fragments). No LDS/barriers in the stream.
__global__ __launch_bounds__(256, 2) void k_gram(
    const float* __restrict__ xin, const float* __restrict__ hist,
    float* __restrict__ Gws)
{
  __shared__ float Gs[KK][KK + 5];

  const int tile = blockIdx.x;
  const int gx = tile / NGY, gy = tile % NGY;
  const size_t base = (size_t)(gx * NGS) * NYY + (size_t)(gy * NGS);
  const int tid  = threadIdx.x;
  const int wave = tid >> 6;
  const int lane = tid & 63;
  const int u    = lane >> 4;
  const int col  = lane & 15;
  const bool tail = (u == 3);
  const int off  = tail ? 17 : (8 * u);

  f32x4 accG[10];
  f32x4 accA[4];
  #pragma unroll
  for (int j = 0; j < 10; ++j) { accG[j].x = 0.f; accG[j].y = 0.f; accG[j].z = 0.f; accG[j].w = 0.f; }
  #pragma unroll
  for (int j = 0; j < 4; ++j) { accA[j].x = 0.f; accA[j].y = 0.f; accA[j].z = 0.f; accA[j].w = 0.f; }

  const int xch = (col < 4) ? col : 3;

  const float* pbase[5];
  #pragma unroll
  for (int s = 0; s < 4; ++s) pbase[s] = hist + (size_t)(16 * s + col) * 1000000 + base + off;
  pbase[4] = xin + (size_t)xch * 1000000 + base + off;

  float bufA[40], bufB[40];

#define LOADIT(BUF, I) { \
    const int r_ = wave + 4 * (I); \
    const size_t ro_ = (size_t)((r_ < NGS) ? r_ : 0) * NYY; \
    _Pragma("unroll") \
    for (int s_ = 0; s_ < 5; ++s_) { \
      _Pragma("unroll") \
      for (int e_ = 0; e_ < 8; ++e_) BUF[s_ * 8 + e_] = pbase[s_][ro_ + e_]; \
    } }

#define CONSUME(BUF, I) { \
    const int r_ = wave + 4 * (I); \
    const bool ok_ = (r_ < NGS); \
    short8 fh[5], fl[5]; \
    _Pragma("unroll") \
    for (int s_ = 0; s_ < 5; ++s_) { \
      _Pragma("unroll") \
      for (int e_ = 0; e_ < 8; ++e_) { \
        float x_ = BUF[s_ * 8 + e_]; \
        if (tail) x_ = (e_ == 0) ? BUF[s_ * 8 + 7] : 0.f; \
        if (!ok_) x_ = 0.f; \
        if (s_ == 4 && col >= 4) x_ = 0.f; \
        const short h_ = (short)(__float_as_uint(x_) >> 16); \
        fh[s_][e_] = h_; \
        fl[s_][e_] = bf16_rn(x_ - bf16_tof(h_)); \
      } \
    } \
    _Pragma("unroll") \
    for (int si_ = 0; si_ < 4; ++si_) \
      _Pragma("unroll") \
      for (int sj_ = 0; sj_ < 4; ++sj_) { \
        if (sj_ >= si_) { \
          const int ix_ = si_ * 4 - (si_ * (si_ + 1)) / 2 + sj_; \
          accG[ix_] = __builtin_amdgcn_mfma_f32_16x16x32_bf16(fh[si_], fh[sj_], accG[ix_], 0, 0, 0); \
          accG[ix_] = __builtin_amdgcn_mfma_f32_16x16x32_bf16(fh[si_], fl[sj_], accG[ix_], 0, 0, 0); \
          accG[ix_] = __builtin_amdgcn_mfma_f32_16x16x32_bf16(fl[si_], fh[sj_], accG[ix_], 0, 0, 0); \
        } \
      } \
    _Pragma("unroll") \
    for (int s_ = 0; s_ < 4; ++s_) { \
      accA[s_] = __builtin_amdgcn_mfma_f32_16x16x32_bf16(fh[4], fh[s_], accA[s_], 0, 0, 0); \
      accA[s_] = __builtin_amdgcn_mfma_f32_16x16x32_bf16(fh[4], fl[s_], accA[s_], 0, 0, 0); \
      accA[s_] = __builtin_amdgcn_mfma_f32_16x16x32_bf16(fl[4], fh[s_], accA[s_], 0, 0, 0); \
    } }

  LOADIT(bufA, 0)
  LOADIT(bufB, 1) CONSUME(bufA, 0)
  LOADIT(bufA, 2) CONSUME(bufB, 1)
  LOADIT(bufB, 3) CONSUME(bufA, 2)
  LOADIT(bufA, 4) CONSUME(bufB, 3)
  LOADIT(bufB, 5) CONSUME(bufA, 4)
  LOADIT(bufA, 6) CONSUME(bufB, 5)
  CONSUME(bufA, 6)

#undef LOADIT
#undef CONSUME

  // ---- cross-wave reduction into Gs (+damping, symmetric mirror) -----------
  __syncthreads();
  for (int g = 0; g < 4; ++g) {
    if (wave == g) {
      #pragma unroll
      for (int si = 0; si < 4; ++si)
        #pragma unroll
        for (int sj = 0; sj < 4; ++sj) {
          if (sj >= si) {
            const int ix = si * 4 - (si * (si + 1)) / 2 + sj;
            #pragma unroll
            for (int q = 0; q < 4; ++q) {
              const float val = (q == 0) ? accG[ix].x : (q == 1) ? accG[ix].y
                              : (q == 2) ? accG[ix].z : accG[ix].w;
              const int r0 = 16 * si + 4 * u + q;
              const int c0 = 16 * sj + col;
              if (g == 0) {
                Gs[r0][c0] = val + ((r0 == c0) ? DAMP : 0.f);
                if (si != sj) Gs[c0][r0] = val;
              } else {
                Gs[r0][c0] += val;
                if (si != sj) Gs[c0][r0] += val;
              }
            }
          }
        }
      if (lane < 16) {
        #pragma unroll
        for (int s = 0; s < 4; ++s) {
          #pragma unroll
          for (int q = 0; q < 4; ++q) {
            const float val = (q == 0) ? accA[s].x : (q == 1) ? accA[s].y
                            : (q == 2) ? accA[s].z : accA[s].w;
            if (g == 0) Gs[16 * s + lane][KK + q] = val;
            else        Gs[16 * s + lane][KK + q] += val;
          }
        }
      }
    }
    __syncthreads();
  }

  // ---- write 64x68 panel (G | A^T) to workspace, coalesced ------------------
  float* dst = Gws + (size_t)tile * (KK * 68);
  for (int idx = tid; idx < KK * 68; idx += 256) {
    const int r = idx / 68, c = idx - r * 68;
    dst[idx] = Gs[r][c];
  }
}

// ---------------- Kernel 1b: per-tile register Gauss-Jordan solve -> AG ------
__global__ __launch_bounds__(256) void k_solve(
    const float* __restrict__ Gws, float* __restrict__ AG)
{
  __shared__ float prow[144];
  const int tile = blockIdx.x;
  const int tid  = threadIdx.x;
  const int lane = tid & 63;
  const int ei = tid >> 2, eq = tid & 3;
  const float* Gt = Gws + (size_t)tile * (KK * 68);

  float w[17];
  #pragma unroll
  for (int jj = 0; jj < 17; ++jj) w[jj] = Gt[ei * 68 + 4 * jj + eq];

  float myDiag = 1.f;
  if (ei == 0) {
    #pragma unroll
    for (int jj = 0; jj < 17; ++jj) prow[4 * jj + eq] = w[jj];
  }
  __syncthreads();

  #pragma unroll
  for (int k = 0; k < KK; ++k) {
    const float* pr = prow + (k & 1) * 72;
    const float piv = pr[k];
    const float num = __shfl(w[k >> 2], (lane & ~3) | (k & 3), 64);
    const float f = (ei == k) ? 0.f : (num / piv);
    if (ei == k) myDiag = piv;
    #pragma unroll
    for (int jj = (k < 3 ? 0 : (k - 2) >> 2); jj < 17; ++jj)
      w[jj] -= f * pr[4 * jj + eq];
    if (k < KK - 1) {
      if (ei == k + 1) {
        float* pw = prow + ((k + 1) & 1) * 72;
        #pragma unroll
        for (int jj = 0; jj < 17; ++jj) pw[4 * jj + eq] = w[jj];
      }
    }
    __syncthreads();
  }

  AG[(size_t)tile * 256 + eq * 64 + ei] = w[16] / myDiag;
}

// ---------------- Kernel 2: coalesced row-strip Y = AG * V -------------------
// Block = one image row (1000 px across 40 gy-tiles). AG for the row's tiles
// staged in LDS transposed to [gy][k][c] (pad 260 to spread banks). hist rows
// read as contiguous float4 (250 lanes x 16B = 4KB contiguous per plane-row).
__global__ __launch_bounds__(256) void k_project(
    const float* __restrict__ hist, const float* __restrict__ AG,
    float* __restrict__ out)
{
  __shared__ float ag[NGY * 260];
  const int i  = blockIdx.x;          // image row 0..999
  const int gx = i / NGS;
  const int tid = threadIdx.x;

  for (int idx = tid; idx < NGY * 256; idx += 256) {
    const int t = idx >> 8, rem = idx & 255;
    const int c = rem >> 6, k = rem & 63;
    ag[t * 260 + k * 4 + c] = AG[(size_t)(gx * NGY + t) * 256 + rem];
  }
  __syncthreads();

  const int py0 = 4 * tid;
  if (py0 < NYY) {
    const int g0 = (py0    ) / NGS, g1 = (py0 + 1) / NGS;
    const int g2 = (py0 + 2) / NGS, g3 = (py0 + 3) / NGS;
    f32x4 o0 = {0,0,0,0}, o1 = {0,0,0,0}, o2 = {0,0,0,0}, o3 = {0,0,0,0};
    const float* hp = hist + (size_t)i * NYY + py0;
    #pragma unroll 8
    for (int k = 0; k < KK; ++k) {
      const float4 v = *(const float4*)(hp + (size_t)k * 1000000);
      const f32x4 a0 = *(const f32x4*)&ag[g0 * 260 + k * 4];
      const f32x4 a1 = *(const f32x4*)&ag[g1 * 260 + k * 4];
      const f32x4 a2 = *(const f32x4*)&ag[g2 * 260 + k * 4];
      const f32x4 a3 = *(const f32x4*)&ag[g3 * 260 + k * 4];
      o0 += a0 * v.x; o1 += a1 * v.y; o2 += a2 * v.z; o3 += a3 * v.w;
    }
    #pragma unroll
    for (int c = 0; c < 4; ++c) {
      float4 w4;
      w4.x = o0[c]; w4.y = o1[c]; w4.z = o2[c]; w4.w = o3[c];
      *(float4*)(out + (size_t)c * 1000000 + (size_t)i * NYY + py0) = w4;
    }
  }
}

extern "C" void kernel_launch(void* const* d_in, const int* in_sizes, int n_in,
                              void* d_out, int out_size, void* d_ws, size_t ws_size,
                              hipStream_t stream) {
  const float* xin  = (const float*)d_in[0];   // local_x  (1,4,1000,1000)
  const float* hist = (const float*)d_in[1];   // ms_history (1,16,4,1000,1000)
  float* out = (float*)d_out;
  float* AG  = (float*)d_ws;                       // 1600*256 floats = 1.6 MB
  float* Gws = (float*)d_ws + 1600 * 256;          // 1600 * 64*68 floats = 27.9 MB

  k_gram   <<<NGX * NGY, 256, 0, stream>>>(xin, hist, Gws);
  k_solve  <<<NGX * NGY, 256, 0, stream>>>(Gws, AG);
  k_project<<<NYY, 256, 0, stream>>>(hist, AG, out);
}